// Round 7
// baseline (495.236 us; speedup 1.0000x reference)
//
#include <hip/hip_runtime.h>
#include <hip/hip_bf16.h>
#include <cstdint>

// Problem constants
static constexpr int Bc  = 4;
static constexpr int Sc  = 8192;
static constexpr int Dc  = 1024;
static constexpr int Hc  = 16;
static constexpr int BHc = Bc * Hc;   // 64
static constexpr int Mc  = Bc * Sc;   // 32768
static constexpr int N3c = 3 * Dc;    // 3072
static constexpr float EPSc = 1e-6f;

using bf16x8 = __attribute__((ext_vector_type(8))) __bf16;
using f32x4  = __attribute__((ext_vector_type(4))) float;

__device__ __forceinline__ ushort f2bf(float f) {
  union { float f; uint32_t u; } v; v.f = f;
  uint32_t u = v.u;
  return (ushort)((u + 0x7fffu + ((u >> 16) & 1u)) >> 16);  // RNE
}
__device__ __forceinline__ float bf2f(ushort h) {
  union { uint32_t u; float f; } v; v.u = ((uint32_t)h) << 16;
  return v.f;
}

typedef const __attribute__((address_space(1))) unsigned int* gas_u32p;
typedef __attribute__((address_space(3))) unsigned int* las_u32p;
__device__ __forceinline__ void gld_lds16(const void* g, void* l) {
  __builtin_amdgcn_global_load_lds((gas_u32p)g, (las_u32p)l, 16, 0, 0);
}

// ---------------------------------------------------------------- kernel 0: fp32 -> bf16 convert (x)
__global__ __launch_bounds__(256) void cvt_bf16_k(const float* __restrict__ src,
                                                  ushort* __restrict__ dst, int n4) {
  for (int i = blockIdx.x * 256 + threadIdx.x; i < n4; i += gridDim.x * 256) {
    float4 v = reinterpret_cast<const float4*>(src)[i];
    ushort4 o; o.x = f2bf(v.x); o.y = f2bf(v.y); o.z = f2bf(v.z); o.w = f2bf(v.w);
    reinterpret_cast<ushort4*>(dst)[i] = o;
  }
}

// ---------------------------------------------------------------- kernel 1: weight fold
// rows 0..1023: W_p@W_Q, bias=W_p b_Q+b_p; 1024..2047: W_p@W_K likewise; 2048..3071: W_V, b_V.
__global__ __launch_bounds__(256) void fold_k(const float* __restrict__ Wq,
                                              const float* __restrict__ Wp,
                                              const float* __restrict__ bq,
                                              const float* __restrict__ bp,
                                              ushort* __restrict__ W3b,
                                              float* __restrict__ bias3) {
  const int bx = blockIdx.x;          // 0..47
  const int p = bx >> 4, h = bx & 15;
  const int t = threadIdx.x;
  if (p == 2) {
    const int base = 2048 + h * 64;
    for (int li = t; li < 64 * 256; li += 256) {
      int r = li >> 8, c4 = (li & 255) * 4;
      float4 v = *reinterpret_cast<const float4*>(&Wq[(size_t)(base + r) * 1024 + c4]);
      ushort4 o; o.x = f2bf(v.x); o.y = f2bf(v.y); o.z = f2bf(v.z); o.w = f2bf(v.w);
      *reinterpret_cast<ushort4*>(&W3b[(size_t)(base + r) * 1024 + c4]) = o;
    }
    if (t < 64) bias3[base + t] = bq[base + t];
    return;
  }
  __shared__ ushort Ws[64 * 64];    // [a][hd]
  __shared__ ushort Tq[256 * 64];   // [d][hd]
  const int rbase = p * 1024 + h * 64;
  for (int li = t; li < 64 * 16; li += 256) {
    int a = li >> 4, h4 = (li & 15) * 4;
    float4 v = *reinterpret_cast<const float4*>(&Wp[a * 64 + h4]);
    ushort4 o; o.x = f2bf(v.x); o.y = f2bf(v.y); o.z = f2bf(v.z); o.w = f2bf(v.w);
    *reinterpret_cast<ushort4*>(&Ws[a * 64 + h4]) = o;
  }
  if (t < 64) {
    float s = bp[t];
    for (int hd = 0; hd < 64; ++hd) s += Wp[t * 64 + hd] * bq[rbase + hd];
    bias3[rbase + t] = s;
  }
  const int w = t >> 6, lane = t & 63, lr = lane & 15, kg = lane >> 4;
  for (int dt = 0; dt < 4; ++dt) {
    __syncthreads();
    for (int li = t; li < 64 * 64; li += 256) {
      int hd = li >> 6, d4 = (li & 63) * 4;
      float4 v = *reinterpret_cast<const float4*>(&Wq[(size_t)(rbase + hd) * 1024 + dt * 256 + d4]);
      Tq[(d4 + 0) * 64 + hd] = f2bf(v.x);
      Tq[(d4 + 1) * 64 + hd] = f2bf(v.y);
      Tq[(d4 + 2) * 64 + hd] = f2bf(v.z);
      Tq[(d4 + 3) * 64 + hd] = f2bf(v.w);
    }
    __syncthreads();
    f32x4 acc[4][4];
#pragma unroll
    for (int i = 0; i < 4; i++)
#pragma unroll
      for (int j = 0; j < 4; j++) acc[i][j] = (f32x4){0.f, 0.f, 0.f, 0.f};
#pragma unroll
    for (int kk = 0; kk < 2; ++kk) {
      bf16x8 af[4], bfr[4];
#pragma unroll
      for (int i = 0; i < 4; i++)
        af[i] = *reinterpret_cast<const bf16x8*>(&Ws[(i * 16 + lr) * 64 + kk * 32 + kg * 8]);
#pragma unroll
      for (int j = 0; j < 4; j++)
        bfr[j] = *reinterpret_cast<const bf16x8*>(&Tq[(w * 64 + j * 16 + lr) * 64 + kk * 32 + kg * 8]);
#pragma unroll
      for (int i = 0; i < 4; i++)
#pragma unroll
        for (int j = 0; j < 4; j++)
          acc[i][j] = __builtin_amdgcn_mfma_f32_16x16x32_bf16(af[i], bfr[j], acc[i][j], 0, 0, 0);
    }
#pragma unroll
    for (int i = 0; i < 4; i++)
#pragma unroll
      for (int j = 0; j < 4; j++)
#pragma unroll
        for (int r = 0; r < 4; r++)
          W3b[(size_t)(rbase + i * 16 + kg * 4 + r) * 1024 + dt * 256 + w * 64 + j * 16 + lr] =
              f2bf(acc[i][j][r]);
  }
}

// ---------------------------------------------------------------- kernel 2: pipelined QKV GEMM + fused phi
// 256x256 tile, BK=32, 8 waves. A: 4-buf LDS ring (64 KB), conflict-free XOR swizzle,
// depth-3 gld_lds prefetch. B: LDS-FREE — register fragments loaded straight from W3b
// (L2-resident via XCD swizzle: each XCD owns a 3 MB W-slice), double-banked 1 ahead.
// One vmcnt(6) + one barrier per K-tile. Outputs:
//   phiQ -> [B,H,S,64] bf16,  phiK -> [B,H,64,S] bf16 (T),  V -> [B,H,64,S] bf16 (T)
__global__ __launch_bounds__(512, 2) void gemm_pipe_k(const ushort* __restrict__ xb,
                                                      const ushort* __restrict__ W3b,
                                                      const float* __restrict__ bias3,
                                                      ushort* __restrict__ Qb,
                                                      ushort* __restrict__ KTb,
                                                      ushort* __restrict__ VTb) {
  __shared__ __align__(16) ushort As[4 * 8192];   // 4 bufs x [256 rows][32 k] = 64 KB
  const int t = threadIdx.x, wave = t >> 6, lane = t & 63;
  const int lr = lane & 15, kg = lane >> 4;
  const int wr = wave >> 2, wc = wave & 3;

  // XCD swizzle, W-residency aware: XCD id = flat&7 = (m-super 2b, n-super 1b).
  // Within an XCD: n fastest over 6 n-tiles (1536 W-rows = 3 MB <= 4 MB L2),
  // so the W-slice stays L2-hot while A streams.
  const int flat = blockIdx.x;
  const int xcd = flat & 7, idx = flat >> 3;     // idx 0..191
  const int m0 = ((xcd >> 1) * 32 + idx / 6) * 256;
  const int n0 = ((xcd & 1) * 6 + idx % 6) * 256;

  // A staging (per tile: 2 gld_lds per wave, 16 KB total). lane covers
  // (row = wave*16 + l>>2, pos = l&3); swizzle g = pos ^ ((row>>1)&3) = (t&3)^((t>>3)&3).
  const int srow = t >> 2;                          // row within 128-row half
  const int sg   = (t & 3) ^ ((t >> 3) & 3);        // global 8-elem col chunk
  const int swb  = wave * 512;                      // wave-uniform lds elem base

  auto stageA = [&](int tile, int buf) {
#pragma unroll
    for (int is = 0; is < 2; ++is)
      gld_lds16(xb + (size_t)(m0 + is * 128 + srow) * 1024 + tile * 32 + sg * 8,
                As + buf * 8192 + is * 4096 + swb);
  };

  const int n0w = n0 + wc * 64;
  auto loadB = [&](int tile, bf16x8 (&bb)[4]) {
#pragma unroll
    for (int j = 0; j < 4; ++j)
      bb[j] = *reinterpret_cast<const bf16x8*>(
          W3b + (size_t)(n0w + j * 16 + lr) * 1024 + tile * 32 + kg * 8);
  };

  f32x4 acc[8][4];
#pragma unroll
  for (int f = 0; f < 8; f++)
#pragma unroll
    for (int j = 0; j < 4; j++) acc[f][j] = (f32x4){0.f, 0.f, 0.f, 0.f};

  // A read side: chunkpos = kg ^ ((lr>>1)&3) -> conflict-free (2 lanes/granule).
  const int cp = (kg ^ ((lr >> 1) & 3)) * 8;
  const ushort* Ard = As + (wr * 128 + lr) * 32 + cp;

  auto compute = [&](int buf, const bf16x8 (&bb)[4]) {
    const ushort* Ab = Ard + buf * 8192;
    bf16x8 a[4];
#pragma unroll
    for (int f = 0; f < 4; ++f) a[f] = *reinterpret_cast<const bf16x8*>(Ab + f * 512);
    __builtin_amdgcn_s_setprio(1);
#pragma unroll
    for (int f = 0; f < 4; ++f)
#pragma unroll
      for (int j = 0; j < 4; ++j)
        acc[f][j] = __builtin_amdgcn_mfma_f32_16x16x32_bf16(a[f], bb[j], acc[f][j], 0, 0, 0);
    __builtin_amdgcn_s_setprio(0);
#pragma unroll
    for (int f = 0; f < 4; ++f) a[f] = *reinterpret_cast<const bf16x8*>(Ab + (f + 4) * 512);
    __builtin_amdgcn_s_setprio(1);
#pragma unroll
    for (int f = 0; f < 4; ++f)
#pragma unroll
      for (int j = 0; j < 4; ++j)
        acc[f + 4][j] = __builtin_amdgcn_mfma_f32_16x16x32_bf16(a[f], bb[j], acc[f + 4][j], 0, 0, 0);
    __builtin_amdgcn_s_setprio(0);
  };

  bf16x8 b0[4], b1[4];
  // prologue: A tiles 0..2 staged, B(0) loaded; cold full drain once.
  stageA(0, 0); stageA(1, 1); stageA(2, 2);
  loadB(0, b0);
  asm volatile("s_waitcnt vmcnt(0)" ::: "memory");
  __builtin_amdgcn_s_barrier();

  // steady state t=0..27: {stageA(t+3), loadB(t+1), vmcnt(6), compute(t), barrier}.
  // vmcnt(6) leaves exactly {stageA(t+3):2, B(t+1):4} in flight -> A(t),B(t) confirmed.
#pragma unroll 1
  for (int tt = 0; tt < 14; ++tt) {
    const int t0 = tt * 2;
    stageA(t0 + 3, (t0 + 3) & 3);
    loadB(t0 + 1, b1);
    asm volatile("s_waitcnt vmcnt(6)" ::: "memory");
    compute(t0 & 3, b0);
    asm volatile("" ::: "memory");
    __builtin_amdgcn_s_barrier();
    stageA(t0 + 4, (t0 + 4) & 3);
    loadB(t0 + 2, b0);
    asm volatile("s_waitcnt vmcnt(6)" ::: "memory");
    compute((t0 + 1) & 3, b1);
    asm volatile("" ::: "memory");
    __builtin_amdgcn_s_barrier();
  }
  // t=28
  stageA(31, 3);
  loadB(29, b1);
  asm volatile("s_waitcnt vmcnt(6)" ::: "memory");
  compute(0, b0);
  asm volatile("" ::: "memory");
  __builtin_amdgcn_s_barrier();
  // t=29
  loadB(30, b0);
  asm volatile("s_waitcnt vmcnt(4)" ::: "memory");
  compute(1, b1);
  asm volatile("" ::: "memory");
  __builtin_amdgcn_s_barrier();
  // t=30
  loadB(31, b1);
  asm volatile("s_waitcnt vmcnt(4)" ::: "memory");
  compute(2, b0);
  asm volatile("" ::: "memory");
  __builtin_amdgcn_s_barrier();
  // t=31
  asm volatile("s_waitcnt vmcnt(0)" ::: "memory");
  compute(3, b1);

  // epilogue: wave's 64 cols = one head of one part (n0 multiple of 256)
  const int part = n0w >> 10;           // 0=phiQ 1=phiK(T) 2=V(T)
  const int h    = (n0w & 1023) >> 6;
  const int bq   = m0 >> 13;
  const int s_base = (m0 & 8191) + wr * 128;
  float bias[4];
#pragma unroll
  for (int j = 0; j < 4; j++) bias[j] = bias3[n0w + j * 16 + lr];

  if (part == 0) {
    ushort* dst = Qb + ((size_t)(bq * Hc + h)) * Sc * 64;
#pragma unroll
    for (int f = 0; f < 8; f++)
#pragma unroll
      for (int j = 0; j < 4; j++)
#pragma unroll
        for (int r = 0; r < 4; r++) {
          float p = acc[f][j][r] + bias[j];
          dst[(size_t)(s_base + f * 16 + kg * 4 + r) * 64 + j * 16 + lr] =
              f2bf(sqrtf(1.f + p * p));
        }
  } else {
    ushort* dst = ((part == 1) ? KTb : VTb) + ((size_t)(bq * Hc + h)) * 64 * Sc;
#pragma unroll
    for (int f = 0; f < 8; f++) {
      const int s = s_base + f * 16 + kg * 4;
#pragma unroll
      for (int j = 0; j < 4; j++) {
        ushort4 o;
        if (part == 1) {
#pragma unroll
          for (int r = 0; r < 4; r++) {
            float p = acc[f][j][r] + bias[j];
            (&o.x)[r] = f2bf(sqrtf(1.f + p * p));
          }
        } else {
#pragma unroll
          for (int r = 0; r < 4; r++) (&o.x)[r] = f2bf(acc[f][j][r] + bias[j]);
        }
        *reinterpret_cast<ushort4*>(&dst[(size_t)(j * 16 + lr) * Sc + s]) = o;
      }
    }
  }
}

// ---------------------------------------------------------------- kernel 3: KTV + ksum partials (T-layout inputs)
__global__ __launch_bounds__(256) void ktv_part_k(const ushort* __restrict__ KT,
                                                  const ushort* __restrict__ VT,
                                                  float* __restrict__ KTVp,
                                                  float* __restrict__ ksump) {
  __shared__ __align__(16) ushort Ks[64 * 128];
  __shared__ __align__(16) ushort Vs[64 * 128];
  __shared__ float red[64][65];
  const int t = threadIdx.x, chunk = blockIdx.x, bh = blockIdx.y;
  const int wave = t >> 6, lane = t & 63, lr = lane & 15, kg = lane >> 4;
  const size_t hb = (size_t)bh * 64 * Sc;
  const int s0 = chunk * 1024;

  f32x4 acc[4][4];
#pragma unroll
  for (int i = 0; i < 4; i++)
#pragma unroll
    for (int j = 0; j < 4; j++) acc[i][j] = (f32x4){0.f, 0.f, 0.f, 0.f};
  float ks_acc = 0.f;

  const int srl = t >> 4;
  const int scc = (t & 15) ^ ((t >> 4) & 7);
  const int wb  = (t >> 6) * 512;
  const int cR = ((wave * 4 + kg) ^ (lr & 7)) * 8;

  for (int st = 0; st < 8; ++st) {
    const int sb = s0 + st * 128;
    __syncthreads();
#pragma unroll
    for (int is = 0; is < 4; ++is) {
      const int row = is * 16 + srl;
      gld_lds16(KT + hb + (size_t)row * Sc + sb + scc * 8, Ks + is * 2048 + wb);
      gld_lds16(VT + hb + (size_t)row * Sc + sb + scc * 8, Vs + is * 2048 + wb);
    }
    __syncthreads();
    {
      bf16x8 af[4], bfr[4];
#pragma unroll
      for (int i = 0; i < 4; i++)
        af[i] = *reinterpret_cast<const bf16x8*>(&Ks[(i * 16 + lr) * 128 + cR]);
#pragma unroll
      for (int j = 0; j < 4; j++)
        bfr[j] = *reinterpret_cast<const bf16x8*>(&Vs[(j * 16 + lr) * 128 + cR]);
#pragma unroll
      for (int i = 0; i < 4; i++)
#pragma unroll
        for (int j = 0; j < 4; j++)
          acc[i][j] = __builtin_amdgcn_mfma_f32_16x16x32_bf16(af[i], bfr[j], acc[i][j], 0, 0, 0);
    }
    if (t < 64) {
      float s = 0.f;
      for (int e = 0; e < 128; e++) s += bf2f(Ks[t * 128 + e]);
      ks_acc += s;
    }
  }

  __syncthreads();
  for (int li = t; li < 64 * 65; li += 256) (&red[0][0])[li] = 0.f;
  __syncthreads();
  for (int w = 0; w < 4; w++) {
    if (wave == w) {
#pragma unroll
      for (int i = 0; i < 4; i++)
#pragma unroll
        for (int j = 0; j < 4; j++)
#pragma unroll
          for (int r = 0; r < 4; r++)
            red[i * 16 + kg * 4 + r][j * 16 + lr] += acc[i][j][r];
    }
    __syncthreads();
  }
  float* outp = KTVp + ((size_t)bh * 8 + chunk) * 4096;
  for (int li = t; li < 4096; li += 256) outp[li] = red[li >> 6][li & 63];
  if (t < 64) ksump[((size_t)bh * 8 + chunk) * 64 + t] = ks_acc;
}

// ---------------------------------------------------------------- kernel 3b: reduce partials
__global__ __launch_bounds__(256) void ktv_red_k(const float* __restrict__ KTVp,
                                                 const float* __restrict__ ksump,
                                                 float* __restrict__ KTV,
                                                 float* __restrict__ ksum) {
  const int bh = blockIdx.x, t = threadIdx.x;
  for (int li = t; li < 4096; li += 256) {
    float s = 0.f;
    for (int c = 0; c < 8; c++) s += KTVp[((size_t)bh * 8 + c) * 4096 + li];
    KTV[(size_t)bh * 4096 + li] = s;
  }
  if (t < 64) {
    float s = 0.f;
    for (int c = 0; c < 8; c++) s += ksump[((size_t)bh * 8 + c) * 64 + t];
    ksum[bh * 64 + t] = s;
  }
}

// ---------------------------------------------------------------- kernel 4: numerator + denominator + output
__global__ __launch_bounds__(256) void out_k(const ushort* __restrict__ Qphi,
                                             const float* __restrict__ KTV,
                                             const float* __restrict__ ksum,
                                             float* __restrict__ out) {
  __shared__ ushort Qs[256][72];
  __shared__ ushort BT[64][72];     // KTV^T in bf16: BT[v][a]
  __shared__ float  den[256];
  __shared__ float  kss[64];
  const int t = threadIdx.x;
  const int bh = blockIdx.y, s0 = blockIdx.x * 256;
  const ushort* qb = Qphi + (size_t)bh * Sc * 64 + (size_t)s0 * 64;

#pragma unroll
  for (int i = 0; i < 8; i++) {
    int li = i * 256 + t;
    int r = li >> 3, c8 = li & 7;
    *reinterpret_cast<uint4*>(&Qs[r][c8 * 8]) = *reinterpret_cast<const uint4*>(&qb[li * 8]);
  }
  for (int li = t; li < 4096; li += 256) {
    int a = li >> 6, v = li & 63;
    BT[v][a] = f2bf(KTV[(size_t)bh * 4096 + li]);
  }
  if (t < 64) kss[t] = ksum[bh * 64 + t];
  __syncthreads();

  {
    float d = 0.f;
    for (int a = 0; a < 64; a++) d += bf2f(Qs[t][a]) * kss[a];
    den[t] = d + EPSc;
  }
  __syncthreads();

  const int wave = t >> 6, lane = t & 63, lr = lane & 15, kg = lane >> 4;
  f32x4 acc[4][4];
#pragma unroll
  for (int i = 0; i < 4; i++)
#pragma unroll
    for (int j = 0; j < 4; j++) acc[i][j] = (f32x4){0.f, 0.f, 0.f, 0.f};

#pragma unroll
  for (int ks = 0; ks < 64; ks += 32) {
    bf16x8 af[4], bfr[4];
#pragma unroll
    for (int i = 0; i < 4; i++)
      af[i] = *reinterpret_cast<const bf16x8*>(&Qs[wave * 64 + i * 16 + lr][ks + kg * 8]);
#pragma unroll
    for (int j = 0; j < 4; j++)
      bfr[j] = *reinterpret_cast<const bf16x8*>(&BT[j * 16 + lr][ks + kg * 8]);
#pragma unroll
    for (int i = 0; i < 4; i++)
#pragma unroll
      for (int j = 0; j < 4; j++)
        acc[i][j] = __builtin_amdgcn_mfma_f32_16x16x32_bf16(af[i], bfr[j], acc[i][j], 0, 0, 0);
  }

  const int bq = bh >> 4, h = bh & 15;
#pragma unroll
  for (int i = 0; i < 4; i++) {
#pragma unroll
    for (int j = 0; j < 4; j++) {
#pragma unroll
      for (int r = 0; r < 4; r++) {
        int row = wave * 64 + i * 16 + kg * 4 + r;
        int s = s0 + row;
        int v = j * 16 + lr;
        out[((size_t)bq * Sc + s) * 1024 + h * 64 + v] = acc[i][j][r] / den[row];
      }
    }
  }
}

// ---------------------------------------------------------------- launch
extern "C" void kernel_launch(void* const* d_in, const int* in_sizes, int n_in,
                              void* d_out, int out_size, void* d_ws, size_t ws_size,
                              hipStream_t stream) {
  const float* x     = (const float*)d_in[0];
  const float* W_qkv = (const float*)d_in[1];
  const float* b_qkv = (const float*)d_in[2];
  const float* W_p   = (const float*)d_in[3];
  const float* b_p   = (const float*)d_in[4];
  float* out = (float*)d_out;

  size_t off = 0;
  auto carve = [&](size_t bytes) -> void* {
    void* p = (char*)d_ws + off;
    off += (bytes + 255) & ~(size_t)255;
    return p;
  };
  const size_t headElems = (size_t)BHc * Sc * 64;           // 33,554,432
  ushort* xb    = (ushort*)carve((size_t)Mc * Dc * 2);      // 64 MB
  ushort* Qb    = (ushort*)carve(headElems * 2);            // phiQ  [B,H,S,64]
  ushort* KTb   = (ushort*)carve(headElems * 2);            // phiK  [B,H,64,S]
  ushort* VTb   = (ushort*)carve(headElems * 2);            // V     [B,H,64,S]
  ushort* W3b   = (ushort*)carve((size_t)N3c * Dc * 2);
  float*  bias3 = (float*)carve((size_t)N3c * 4);
  float*  KTVp  = (float*)carve((size_t)BHc * 8 * 4096 * 4);
  float*  ksmp  = (float*)carve((size_t)BHc * 8 * 64 * 4);
  float*  KTV   = (float*)carve((size_t)BHc * 4096 * 4);
  float*  ksum  = (float*)carve((size_t)BHc * 64 * 4);
  (void)ws_size; (void)n_in; (void)in_sizes; (void)out_size;

  cvt_bf16_k<<<2048, 256, 0, stream>>>(x, xb, Mc * Dc / 4);
  fold_k<<<48, 256, 0, stream>>>(W_qkv, W_p, b_qkv, b_p, W3b, bias3);
  gemm_pipe_k<<<(Mc / 256) * (N3c / 256), 512, 0, stream>>>(xb, W3b, bias3, Qb, KTb, VTb);
  ktv_part_k<<<dim3(8, BHc), 256, 0, stream>>>(KTb, VTb, KTVp, ksmp);
  ktv_red_k<<<BHc, 256, 0, stream>>>(KTVp, ksmp, KTV, ksum);
  out_k<<<dim3(Sc / 256, BHc), 256, 0, stream>>>(Qb, KTV, ksum, out);
}

// Round 8
// 422.963 us; speedup vs baseline: 1.1709x; 1.1709x over previous
//
#include <hip/hip_runtime.h>
#include <hip/hip_bf16.h>
#include <cstdint>

// Problem constants
static constexpr int Bc  = 4;
static constexpr int Sc  = 8192;
static constexpr int Dc  = 1024;
static constexpr int Hc  = 16;
static constexpr int BHc = Bc * Hc;   // 64
static constexpr int Mc  = Bc * Sc;   // 32768
static constexpr int N3c = 3 * Dc;    // 3072
static constexpr float EPSc = 1e-6f;

using bf16x8 = __attribute__((ext_vector_type(8))) __bf16;
using f32x4  = __attribute__((ext_vector_type(4))) float;

__device__ __forceinline__ ushort f2bf(float f) {
  union { float f; uint32_t u; } v; v.f = f;
  uint32_t u = v.u;
  return (ushort)((u + 0x7fffu + ((u >> 16) & 1u)) >> 16);  // RNE
}
__device__ __forceinline__ float bf2f(ushort h) {
  union { uint32_t u; float f; } v; v.u = ((uint32_t)h) << 16;
  return v.f;
}

typedef const __attribute__((address_space(1))) unsigned int* gas_u32p;
typedef __attribute__((address_space(3))) unsigned int* las_u32p;
__device__ __forceinline__ void gld_lds16(const void* g, void* l) {
  __builtin_amdgcn_global_load_lds((gas_u32p)g, (las_u32p)l, 16, 0, 0);
}

// ---------------------------------------------------------------- kernel 0: fp32 -> bf16 convert (x)
__global__ __launch_bounds__(256) void cvt_bf16_k(const float* __restrict__ src,
                                                  ushort* __restrict__ dst, int n4) {
  for (int i = blockIdx.x * 256 + threadIdx.x; i < n4; i += gridDim.x * 256) {
    float4 v = reinterpret_cast<const float4*>(src)[i];
    ushort4 o; o.x = f2bf(v.x); o.y = f2bf(v.y); o.z = f2bf(v.z); o.w = f2bf(v.w);
    reinterpret_cast<ushort4*>(dst)[i] = o;
  }
}

// ---------------------------------------------------------------- kernel 1: weight fold
// rows 0..1023: W_p@W_Q, bias=W_p b_Q+b_p; 1024..2047: W_p@W_K likewise; 2048..3071: W_V, b_V.
__global__ __launch_bounds__(256) void fold_k(const float* __restrict__ Wq,
                                              const float* __restrict__ Wp,
                                              const float* __restrict__ bq,
                                              const float* __restrict__ bp,
                                              ushort* __restrict__ W3b,
                                              float* __restrict__ bias3) {
  const int bx = blockIdx.x;          // 0..47
  const int p = bx >> 4, h = bx & 15;
  const int t = threadIdx.x;
  if (p == 2) {
    const int base = 2048 + h * 64;
    for (int li = t; li < 64 * 256; li += 256) {
      int r = li >> 8, c4 = (li & 255) * 4;
      float4 v = *reinterpret_cast<const float4*>(&Wq[(size_t)(base + r) * 1024 + c4]);
      ushort4 o; o.x = f2bf(v.x); o.y = f2bf(v.y); o.z = f2bf(v.z); o.w = f2bf(v.w);
      *reinterpret_cast<ushort4*>(&W3b[(size_t)(base + r) * 1024 + c4]) = o;
    }
    if (t < 64) bias3[base + t] = bq[base + t];
    return;
  }
  __shared__ ushort Ws[64 * 64];    // [a][hd]
  __shared__ ushort Tq[256 * 64];   // [d][hd]
  const int rbase = p * 1024 + h * 64;
  for (int li = t; li < 64 * 16; li += 256) {
    int a = li >> 4, h4 = (li & 15) * 4;
    float4 v = *reinterpret_cast<const float4*>(&Wp[a * 64 + h4]);
    ushort4 o; o.x = f2bf(v.x); o.y = f2bf(v.y); o.z = f2bf(v.z); o.w = f2bf(v.w);
    *reinterpret_cast<ushort4*>(&Ws[a * 64 + h4]) = o;
  }
  if (t < 64) {
    float s = bp[t];
    for (int hd = 0; hd < 64; ++hd) s += Wp[t * 64 + hd] * bq[rbase + hd];
    bias3[rbase + t] = s;
  }
  const int w = t >> 6, lane = t & 63, lr = lane & 15, kg = lane >> 4;
  for (int dt = 0; dt < 4; ++dt) {
    __syncthreads();
    for (int li = t; li < 64 * 64; li += 256) {
      int hd = li >> 6, d4 = (li & 63) * 4;
      float4 v = *reinterpret_cast<const float4*>(&Wq[(size_t)(rbase + hd) * 1024 + dt * 256 + d4]);
      Tq[(d4 + 0) * 64 + hd] = f2bf(v.x);
      Tq[(d4 + 1) * 64 + hd] = f2bf(v.y);
      Tq[(d4 + 2) * 64 + hd] = f2bf(v.z);
      Tq[(d4 + 3) * 64 + hd] = f2bf(v.w);
    }
    __syncthreads();
    f32x4 acc[4][4];
#pragma unroll
    for (int i = 0; i < 4; i++)
#pragma unroll
      for (int j = 0; j < 4; j++) acc[i][j] = (f32x4){0.f, 0.f, 0.f, 0.f};
#pragma unroll
    for (int kk = 0; kk < 2; ++kk) {
      bf16x8 af[4], bfr[4];
#pragma unroll
      for (int i = 0; i < 4; i++)
        af[i] = *reinterpret_cast<const bf16x8*>(&Ws[(i * 16 + lr) * 64 + kk * 32 + kg * 8]);
#pragma unroll
      for (int j = 0; j < 4; j++)
        bfr[j] = *reinterpret_cast<const bf16x8*>(&Tq[(w * 64 + j * 16 + lr) * 64 + kk * 32 + kg * 8]);
#pragma unroll
      for (int i = 0; i < 4; i++)
#pragma unroll
        for (int j = 0; j < 4; j++)
          acc[i][j] = __builtin_amdgcn_mfma_f32_16x16x32_bf16(af[i], bfr[j], acc[i][j], 0, 0, 0);
    }
#pragma unroll
    for (int i = 0; i < 4; i++)
#pragma unroll
      for (int j = 0; j < 4; j++)
#pragma unroll
        for (int r = 0; r < 4; r++)
          W3b[(size_t)(rbase + i * 16 + kg * 4 + r) * 1024 + dt * 256 + w * 64 + j * 16 + lr] =
              f2bf(acc[i][j][r]);
  }
}

// ---------------------------------------------------------------- kernel 2: pipelined QKV GEMM + fused phi
// (round-5 champion, verbatim) 256x256 tile, BK=32, 8 waves, 4-buffer LDS ring (depth-3
// prefetch), counted vmcnt(8), raw barriers, exact conflict-free both-sides XOR swizzle.
__global__ __launch_bounds__(512, 2) void gemm_pipe_k(const ushort* __restrict__ xb,
                                                      const ushort* __restrict__ W3b,
                                                      const float* __restrict__ bias3,
                                                      ushort* __restrict__ Qb,
                                                      ushort* __restrict__ KTb,
                                                      ushort* __restrict__ VTb) {
  __shared__ __align__(16) ushort As[4 * 8192];   // 4 bufs x [256 rows][32 k] = 64 KB
  __shared__ __align__(16) ushort Bs[4 * 8192];   // 64 KB
  const int t = threadIdx.x, wave = t >> 6, lane = t & 63;
  const int lr = lane & 15, kg = lane >> 4;
  const int wr = wave >> 2, wc = wave & 3;

  // XCD-bijective swizzle: 1536 = 8 * 192; each XCD: 16 m-tiles x 12 n-tiles, n fastest.
  const int flat = blockIdx.x;
  const int swz  = (flat & 7) * 192 + (flat >> 3);
  const int n0 = (swz % 12) * 256;
  const int m0 = (swz / 12) * 256;

  const int srow = t >> 2;                          // row within 128-row half
  const int sg   = (t & 3) ^ ((t >> 3) & 3);        // global 8-elem col chunk
  const int swb  = wave * 512;                      // wave-uniform lds elem base

  auto STAGE = [&](int tile, int buf) {
    const int kt = tile * 32;
#pragma unroll
    for (int is = 0; is < 2; ++is) {
      gld_lds16(xb  + (size_t)(m0 + is * 128 + srow) * 1024 + kt + sg * 8,
                As + buf * 8192 + is * 4096 + swb);
      gld_lds16(W3b + (size_t)(n0 + is * 128 + srow) * 1024 + kt + sg * 8,
                Bs + buf * 8192 + is * 4096 + swb);
    }
  };

  f32x4 acc[8][4];
#pragma unroll
  for (int f = 0; f < 8; f++)
#pragma unroll
    for (int j = 0; j < 4; j++) acc[f][j] = (f32x4){0.f, 0.f, 0.f, 0.f};

  // Read side: chunkpos = kg ^ ((lr>>1)&3) -> balanced (min-issue) bank mapping.
  const int cp = (kg ^ ((lr >> 1) & 3)) * 8;
  const ushort* Ard = As + (wr * 128 + lr) * 32 + cp;   // + f*512 + buf*8192
  const ushort* Brd = Bs + (wc * 64 + lr) * 32 + cp;    // + j*512 + buf*8192

  auto COMPUTE = [&](int buf) {
    bf16x8 af[8], bfr[4];
    const ushort* Ab = Ard + buf * 8192;
    const ushort* Bb = Brd + buf * 8192;
#pragma unroll
    for (int f = 0; f < 8; f++) af[f] = *reinterpret_cast<const bf16x8*>(Ab + f * 512);
#pragma unroll
    for (int j = 0; j < 4; j++) bfr[j] = *reinterpret_cast<const bf16x8*>(Bb + j * 512);
    __builtin_amdgcn_s_setprio(1);
#pragma unroll
    for (int f = 0; f < 8; f++)
#pragma unroll
      for (int j = 0; j < 4; j++)
        acc[f][j] = __builtin_amdgcn_mfma_f32_16x16x32_bf16(af[f], bfr[j], acc[f][j], 0, 0, 0);
    __builtin_amdgcn_s_setprio(0);
  };

  // prologue: stage tiles 0..2 (12 loads), wait tile 0 (8 remain outstanding)
  STAGE(0, 0);
  STAGE(1, 1);
  STAGE(2, 2);
  asm volatile("s_waitcnt vmcnt(8)" ::: "memory");
  __builtin_amdgcn_s_barrier();

#pragma unroll 1
  for (int i = 0; i < 7; ++i) {
    const int tb = i * 4;
#pragma unroll
    for (int j = 0; j < 4; ++j) {
      STAGE(tb + j + 3, (j + 3) & 3);
      COMPUTE(j);
      asm volatile("s_waitcnt vmcnt(8)" ::: "memory");
      __builtin_amdgcn_s_barrier();
    }
  }
  STAGE(31, 3);
  COMPUTE(0);
  asm volatile("s_waitcnt vmcnt(8)" ::: "memory");
  __builtin_amdgcn_s_barrier();
  COMPUTE(1);
  asm volatile("s_waitcnt vmcnt(4)" ::: "memory");
  __builtin_amdgcn_s_barrier();
  COMPUTE(2);
  asm volatile("s_waitcnt vmcnt(0)" ::: "memory");
  __builtin_amdgcn_s_barrier();
  COMPUTE(3);

  // epilogue: wave's 64 cols = one head of one part (n0 multiple of 256)
  const int n0w  = n0 + wc * 64;
  const int part = n0w >> 10;           // 0=phiQ 1=phiK(T) 2=V(T)
  const int h    = (n0w & 1023) >> 6;
  const int bq   = m0 >> 13;
  const int s_base = (m0 & 8191) + wr * 128;
  float bias[4];
#pragma unroll
  for (int j = 0; j < 4; j++) bias[j] = bias3[n0w + j * 16 + lr];

  if (part == 0) {
    ushort* dst = Qb + ((size_t)(bq * Hc + h)) * Sc * 64;
#pragma unroll
    for (int f = 0; f < 8; f++)
#pragma unroll
      for (int j = 0; j < 4; j++)
#pragma unroll
        for (int r = 0; r < 4; r++) {
          float p = acc[f][j][r] + bias[j];
          dst[(size_t)(s_base + f * 16 + kg * 4 + r) * 64 + j * 16 + lr] =
              f2bf(sqrtf(1.f + p * p));
        }
  } else {
    ushort* dst = ((part == 1) ? KTb : VTb) + ((size_t)(bq * Hc + h)) * 64 * Sc;
#pragma unroll
    for (int f = 0; f < 8; f++) {
      const int s = s_base + f * 16 + kg * 4;
#pragma unroll
      for (int j = 0; j < 4; j++) {
        ushort4 o;
        if (part == 1) {
#pragma unroll
          for (int r = 0; r < 4; r++) {
            float p = acc[f][j][r] + bias[j];
            (&o.x)[r] = f2bf(sqrtf(1.f + p * p));
          }
        } else {
#pragma unroll
          for (int r = 0; r < 4; r++) (&o.x)[r] = f2bf(acc[f][j][r] + bias[j]);
        }
        *reinterpret_cast<ushort4*>(&dst[(size_t)(j * 16 + lr) * Sc + s]) = o;
      }
    }
  }
}

// ---------------------------------------------------------------- kernel 3: KTV + ksum partials (T-layout inputs)
// Per-wave partials written straight to global (no cross-wave LDS reduce); ksum computed
// by all 256 threads (4 segments/row). ktv_red sums 32 KTV partials / 32 ksum partials.
__global__ __launch_bounds__(256) void ktv_part_k(const ushort* __restrict__ KT,
                                                  const ushort* __restrict__ VT,
                                                  float* __restrict__ KTVp,
                                                  float* __restrict__ ksump) {
  __shared__ __align__(16) ushort Ks[64 * 128];
  __shared__ __align__(16) ushort Vs[64 * 128];
  const int t = threadIdx.x, chunk = blockIdx.x, bh = blockIdx.y;
  const int wave = t >> 6, lane = t & 63, lr = lane & 15, kg = lane >> 4;
  const size_t hb = (size_t)bh * 64 * Sc;
  const int s0 = chunk * 1024;

  f32x4 acc[4][4];
#pragma unroll
  for (int i = 0; i < 4; i++)
#pragma unroll
    for (int j = 0; j < 4; j++) acc[i][j] = (f32x4){0.f, 0.f, 0.f, 0.f};
  float ks_acc = 0.f;

  const int srl = t >> 4;
  const int scc = (t & 15) ^ ((t >> 4) & 7);
  const int wb  = (t >> 6) * 512;
  const int cR = ((wave * 4 + kg) ^ (lr & 7)) * 8;
  const int ka = t & 63, kh = t >> 6;           // ksum: row a = ka, segment kh

  for (int st = 0; st < 8; ++st) {
    const int sb = s0 + st * 128;
    __syncthreads();
#pragma unroll
    for (int is = 0; is < 4; ++is) {
      const int row = is * 16 + srl;
      gld_lds16(KT + hb + (size_t)row * Sc + sb + scc * 8, Ks + is * 2048 + wb);
      gld_lds16(VT + hb + (size_t)row * Sc + sb + scc * 8, Vs + is * 2048 + wb);
    }
    __syncthreads();
    {
      bf16x8 af[4], bfr[4];
#pragma unroll
      for (int i = 0; i < 4; i++)
        af[i] = *reinterpret_cast<const bf16x8*>(&Ks[(i * 16 + lr) * 128 + cR]);
#pragma unroll
      for (int j = 0; j < 4; j++)
        bfr[j] = *reinterpret_cast<const bf16x8*>(&Vs[(j * 16 + lr) * 128 + cR]);
#pragma unroll
      for (int i = 0; i < 4; i++)
#pragma unroll
        for (int j = 0; j < 4; j++)
          acc[i][j] = __builtin_amdgcn_mfma_f32_16x16x32_bf16(af[i], bfr[j], acc[i][j], 0, 0, 0);
    }
    {  // swizzle permutes within a row only -> row sums unaffected
      float s = 0.f;
#pragma unroll
      for (int e = 0; e < 32; e++) s += bf2f(Ks[ka * 128 + kh * 32 + e]);
      ks_acc += s;
    }
  }

  // per-wave partial KTV: [bh][chunk][wave][64a][64v]
  float* outp = KTVp + (((size_t)bh * 8 + chunk) * 4 + wave) * 4096;
#pragma unroll
  for (int i = 0; i < 4; i++)
#pragma unroll
    for (int j = 0; j < 4; j++)
#pragma unroll
      for (int r = 0; r < 4; r++)
        outp[(i * 16 + kg * 4 + r) * 64 + j * 16 + lr] = acc[i][j][r];
  // per-segment partial ksum: [bh][chunk][seg][64a]
  ksump[(((size_t)bh * 8 + chunk) * 4 + kh) * 64 + ka] = ks_acc;
}

// ---------------------------------------------------------------- kernel 3b: reduce partials (32 each)
__global__ __launch_bounds__(256) void ktv_red_k(const float* __restrict__ KTVp,
                                                 const float* __restrict__ ksump,
                                                 float* __restrict__ KTV,
                                                 float* __restrict__ ksum) {
  const int bh = blockIdx.x, t = threadIdx.x;
  for (int li = t; li < 4096; li += 256) {
    float s = 0.f;
    for (int c = 0; c < 32; c++) s += KTVp[((size_t)bh * 32 + c) * 4096 + li];
    KTV[(size_t)bh * 4096 + li] = s;
  }
  if (t < 64) {
    float s = 0.f;
    for (int c = 0; c < 32; c++) s += ksump[((size_t)bh * 32 + c) * 64 + t];
    ksum[bh * 64 + t] = s;
  }
}

// ---------------------------------------------------------------- kernel 4: numerator + denominator + output
__global__ __launch_bounds__(256) void out_k(const ushort* __restrict__ Qphi,
                                             const float* __restrict__ KTV,
                                             const float* __restrict__ ksum,
                                             float* __restrict__ out) {
  __shared__ ushort Qs[256][72];
  __shared__ ushort BT[64][72];     // KTV^T in bf16: BT[v][a]
  __shared__ float  den[256];
  __shared__ float  kss[64];
  const int t = threadIdx.x;
  const int bh = blockIdx.y, s0 = blockIdx.x * 256;
  const ushort* qb = Qphi + (size_t)bh * Sc * 64 + (size_t)s0 * 64;

#pragma unroll
  for (int i = 0; i < 8; i++) {
    int li = i * 256 + t;
    int r = li >> 3, c8 = li & 7;
    *reinterpret_cast<uint4*>(&Qs[r][c8 * 8]) = *reinterpret_cast<const uint4*>(&qb[li * 8]);
  }
  for (int li = t; li < 4096; li += 256) {
    int a = li >> 6, v = li & 63;
    BT[v][a] = f2bf(KTV[(size_t)bh * 4096 + li]);
  }
  if (t < 64) kss[t] = ksum[bh * 64 + t];
  __syncthreads();

  {
    float d = 0.f;
    for (int a = 0; a < 64; a++) d += bf2f(Qs[t][a]) * kss[a];
    den[t] = d + EPSc;
  }
  __syncthreads();

  const int wave = t >> 6, lane = t & 63, lr = lane & 15, kg = lane >> 4;
  f32x4 acc[4][4];
#pragma unroll
  for (int i = 0; i < 4; i++)
#pragma unroll
    for (int j = 0; j < 4; j++) acc[i][j] = (f32x4){0.f, 0.f, 0.f, 0.f};

#pragma unroll
  for (int ks = 0; ks < 64; ks += 32) {
    bf16x8 af[4], bfr[4];
#pragma unroll
    for (int i = 0; i < 4; i++)
      af[i] = *reinterpret_cast<const bf16x8*>(&Qs[wave * 64 + i * 16 + lr][ks + kg * 8]);
#pragma unroll
    for (int j = 0; j < 4; j++)
      bfr[j] = *reinterpret_cast<const bf16x8*>(&BT[j * 16 + lr][ks + kg * 8]);
#pragma unroll
    for (int i = 0; i < 4; i++)
#pragma unroll
      for (int j = 0; j < 4; j++)
        acc[i][j] = __builtin_amdgcn_mfma_f32_16x16x32_bf16(af[i], bfr[j], acc[i][j], 0, 0, 0);
  }

  const int bq = bh >> 4, h = bh & 15;
#pragma unroll
  for (int i = 0; i < 4; i++) {
#pragma unroll
    for (int j = 0; j < 4; j++) {
#pragma unroll
      for (int r = 0; r < 4; r++) {
        int row = wave * 64 + i * 16 + kg * 4 + r;
        int s = s0 + row;
        int v = j * 16 + lr;
        out[((size_t)bq * Sc + s) * 1024 + h * 64 + v] = acc[i][j][r] / den[row];
      }
    }
  }
}

// ---------------------------------------------------------------- launch
extern "C" void kernel_launch(void* const* d_in, const int* in_sizes, int n_in,
                              void* d_out, int out_size, void* d_ws, size_t ws_size,
                              hipStream_t stream) {
  const float* x     = (const float*)d_in[0];
  const float* W_qkv = (const float*)d_in[1];
  const float* b_qkv = (const float*)d_in[2];
  const float* W_p   = (const float*)d_in[3];
  const float* b_p   = (const float*)d_in[4];
  float* out = (float*)d_out;

  size_t off = 0;
  auto carve = [&](size_t bytes) -> void* {
    void* p = (char*)d_ws + off;
    off += (bytes + 255) & ~(size_t)255;
    return p;
  };
  const size_t headElems = (size_t)BHc * Sc * 64;           // 33,554,432
  ushort* xb    = (ushort*)carve((size_t)Mc * Dc * 2);      // 64 MB
  ushort* Qb    = (ushort*)carve(headElems * 2);            // phiQ  [B,H,S,64]
  ushort* KTb   = (ushort*)carve(headElems * 2);            // phiK  [B,H,64,S]
  ushort* VTb   = (ushort*)carve(headElems * 2);            // V     [B,H,64,S]
  ushort* W3b   = (ushort*)carve((size_t)N3c * Dc * 2);
  float*  bias3 = (float*)carve((size_t)N3c * 4);
  float*  KTVp  = (float*)carve((size_t)BHc * 32 * 4096 * 4);  // 32 partials/bh
  float*  ksmp  = (float*)carve((size_t)BHc * 32 * 64 * 4);
  float*  KTV   = (float*)carve((size_t)BHc * 4096 * 4);
  float*  ksum  = (float*)carve((size_t)BHc * 64 * 4);
  (void)ws_size; (void)n_in; (void)in_sizes; (void)out_size;

  cvt_bf16_k<<<2048, 256, 0, stream>>>(x, xb, Mc * Dc / 4);
  fold_k<<<48, 256, 0, stream>>>(W_qkv, W_p, b_qkv, b_p, W3b, bias3);
  gemm_pipe_k<<<(Mc / 256) * (N3c / 256), 512, 0, stream>>>(xb, W3b, bias3, Qb, KTb, VTb);
  ktv_part_k<<<dim3(8, BHc), 256, 0, stream>>>(KTb, VTb, KTVp, ksmp);
  ktv_red_k<<<BHc, 256, 0, stream>>>(KTVp, ksmp, KTV, ksum);
  out_k<<<dim3(Sc / 256, BHc), 256, 0, stream>>>(Qb, KTV, ksum, out);
}